// Round 11
// baseline (318.165 us; speedup 1.0000x reference)
//
#include <hip/hip_runtime.h>
#include <hip/hip_bf16.h>

// CapsuleLayer dynamic routing. B=64, I=2048, D=16, J=32, K=16, routings=3.
// Structure: uhat never hits HBM; pass recomputes u_hat (MFMA 32x32x16,
// K=d=16 exact, operand maps proven since r15, absmax 0.0039) and uses
// b_t = u_hat . vsum linearity. NEW in r22:
//  - caps_prep packs W -> Wbf (per-i 16KB tiles = exact LDS byte image,
//    512 rows x 32B tight) and x -> xbf (bf16 pairs) ONCE. Passes lose all
//    f32->bf16 VALU + halve W bytes (r21 counters: FETCH=70MB=full f32 W per
//    pass, VALUBusy 9% mostly staging, 1.67TB/s, 62.8us latency-bound).
//  - pass stages via __builtin_amdgcn_global_load_lds (16B/lane, 4 calls/
//    wave/tile, dest = wave-uniform base + lane*16, src per-lane): 2-deep
//    async pipeline, buf^1 in flight across the whole compute of buf p.
//    Only drain: end-of-iter `vmcnt(0) lgkmcnt(0); s_barrier`. Mid-iter
//    ebuf barrier stays lgkm-only (r16/r17 lesson: __syncthreads drains
//    vmcnt; raw barriers preserve DMA overlap).
//  - reduction: redA (grid 256 = j x 8 pg) sums 32 partials via coalesced
//    4KB rows -> part2 (1MB); redB (grid 32 = j) folds 8 + squash. Fixes
//    r21's ~30us/squash 128-KB-stride walk (r19 lesson, reads side).
// Lessons: never force min-waves (r8); coalesced stores only (r13); no
// grid.sync (r19); parenthesize byte-offset shifts (r20).

#define B_ 64
#define I_ 2048
#define D_ 16
#define J_ 32
#define K_ 16
#define JK 512
#define NIC 256   // i-chunks
#define GI 8      // i's per chunk
#define JDK (J_ * D_ * K_)  // 8192 floats per i
#define WTB 16384           // Wbf tile bytes per i (512 rows x 32B)
#define MB(n) ((size_t)(n) << 20)

typedef __attribute__((ext_vector_type(8))) short short8;
typedef __attribute__((ext_vector_type(16))) float float16v;

__device__ __forceinline__ unsigned short f2bf(float f) {
    union { float f; unsigned int i; } v;
    v.f = f;
    const unsigned int x = v.i;
    return (unsigned short)((x + 0x7fffu + ((x >> 16) & 1u)) >> 16);  // RNE
}

// async global->LDS, 16B per lane. LDS dest must be wave-uniform base
// (HW adds lane*16); global src is per-lane.
__device__ __forceinline__ void gld16(const void* g, void* l) {
    __builtin_amdgcn_global_load_lds(
        (const __attribute__((address_space(1))) void*)g,
        (__attribute__((address_space(3))) void*)l, 16, 0, 0);
}

// LDS-only barrier (no vmcnt drain — DMA stays in flight).
__device__ __forceinline__ void bar_lds() {
    asm volatile("s_waitcnt lgkmcnt(0)\n\ts_barrier" ::: "memory");
}
// Full drain barrier: DMA landed + LDS ordered.
__device__ __forceinline__ void bar_all() {
    asm volatile("s_waitcnt vmcnt(0) lgkmcnt(0)\n\ts_barrier" ::: "memory");
}

// ---------------------------------------------------------------------------
// One-shot pack. Blocks 0..I_-1: W[i] -> Wbf tile (rows r=j*16+k, 8 dwords of
// bf16 (d,d+1) pairs, tight 32B pitch). Blocks I_..I_+15: x -> xbf pairs.
// ---------------------------------------------------------------------------
__global__ __launch_bounds__(256)
void caps_prep(const float* __restrict__ x, const float* __restrict__ W,
               unsigned short* __restrict__ Wbf,
               unsigned int* __restrict__ xbf) {
    const int blk = blockIdx.x;
    const int tid = threadIdx.x;
    if (blk < I_) {
        const float* wb = W + (size_t)blk * JDK;
        unsigned short* dst = Wbf + (size_t)blk * (WTB / 2);
#pragma unroll
        for (int rr = 0; rr < 2; ++rr) {
            const int r = tid + rr * 256;
            const float* p = wb + (r >> 4) * (D_ * K_) + (r & 15);
            unsigned int pk[8];
#pragma unroll
            for (int q = 0; q < 8; ++q)
                pk[q] = ((unsigned int)f2bf(p[(2 * q + 1) * K_]) << 16) |
                        f2bf(p[(2 * q) * K_]);
            uint4* d4 = reinterpret_cast<uint4*>(dst + r * 16);
            uint4 w0; w0.x = pk[0]; w0.y = pk[1]; w0.z = pk[2]; w0.w = pk[3];
            uint4 w1; w1.x = pk[4]; w1.y = pk[5]; w1.z = pk[6]; w1.w = pk[7];
            d4[0] = w0; d4[1] = w1;
        }
    } else {
        const int xi = (blk - I_) * 256 + tid;  // 0..4095
        const float4* xs = reinterpret_cast<const float4*>(x);
        uint2* xd = reinterpret_cast<uint2*>(xbf);
        const int nf4 = B_ * I_ * D_ / 4;  // 524288
        for (int n = xi; n < nf4; n += 4096) {
            const float4 v = xs[n];
            uint2 o;
            o.x = ((unsigned int)f2bf(v.y) << 16) | f2bf(v.x);
            o.y = ((unsigned int)f2bf(v.w) << 16) | f2bf(v.z);
            xd[n] = o;
        }
    }
}

// ---------------------------------------------------------------------------
// Routing pass. MODE 0: acc += u_hat. MODE 1: acc += softmax * u_hat.
// Grid (NIC*2) x 256: ic = blockIdx>>1, bh = blockIdx&1 (2 blocks/CU).
// Wave jg = j-octet. Lane: b = bh*32+l31, h = lane>>5.
// MFMA m: A rows (j=jg*8+m*2+jp, k), jp=l31>>4, k=l31&15; C col=b,
// reg r: jp=r>>3, k=(r&3)+8*((r>>2)&1)+4h.  (proven map, absmax 0.0039)
// ---------------------------------------------------------------------------
template <int MODE>
__global__ __launch_bounds__(256)
void caps_pass(const unsigned short* __restrict__ Wbf,
               const uint4* __restrict__ xbf,
               const float* __restrict__ vsum, float* __restrict__ part) {
    __shared__ unsigned short wlds[2][8192];  // 2 x 16 KB
    __shared__ float ebuf[2][4][32];

    const int tid = threadIdx.x;
    const int lane = tid & 63;
    const int jg = tid >> 6;
    const int l31 = lane & 31, h = lane >> 5;
    const int bh = blockIdx.x & 1;
    const int ic = blockIdx.x >> 1;
    const int b = bh * 32 + l31;
    const int i0 = ic * GI;

    float vv[4][2][8];
    if (MODE == 1) {
#pragma unroll
        for (int m = 0; m < 4; ++m)
#pragma unroll
            for (int jp = 0; jp < 2; ++jp)
#pragma unroll
                for (int q = 0; q < 8; ++q) {
                    const int kq = (q & 3) + 8 * ((q >> 2) & 1) + 4 * h;
                    const int s = (jg * 8 + m * 2 + jp) * 16 + kq;
                    vv[m][jp][q] = vsum[(size_t)s * 64 + b];
                }
    }

    float16v acc[4];
#pragma unroll
    for (int m = 0; m < 4; ++m)
#pragma unroll
        for (int r = 0; r < 16; ++r) acc[m][r] = 0.f;

    // DMA addressing: src per-lane, LDS dest wave-uniform (+lane*16 by HW)
    const char* wsrc =
        (const char*)Wbf + (size_t)i0 * WTB + jg * 1024 + lane * 16;
    char* ldsb[2] = {(char*)&wlds[0][0] + jg * 1024,
                     (char*)&wlds[1][0] + jg * 1024};
#define STAGE(tt, pp)                                                    \
    do {                                                                 \
        _Pragma("unroll") for (int c = 0; c < 4; ++c)                    \
            gld16(wsrc + (size_t)(tt)*WTB + c * 4096, ldsb[pp] + c * 4096); \
    } while (0)

    STAGE(0, 0);
    bar_all();   // buf0 landed, visible to all waves
    STAGE(1, 1); // in flight across iter 0

    const int abase = ((jg * 8 + (l31 >> 4)) * 16 + (l31 & 15)) * 16 + h * 8;
    const uint4* xb = xbf + ((size_t)b * I_ + i0) * 2 + h;

    for (int t = 0; t < GI; ++t) {
        const int p = t & 1;
        union { uint4 u; short8 s; } bfrag;
        bfrag.u = xb[t * 2];

        float16v u[4];
#pragma unroll
        for (int m = 0; m < 4; ++m) {
            union { uint4 q; short8 s; } af;
            af.q = *reinterpret_cast<const uint4*>(&wlds[p][abase + m * 512]);
            float16v z;
#pragma unroll
            for (int r = 0; r < 16; ++r) z[r] = 0.f;
            u[m] = __builtin_amdgcn_mfma_f32_32x32x16_bf16(af.s, bfrag.s, z,
                                                           0, 0, 0);
        }

        if (MODE == 0) {
#pragma unroll
            for (int m = 0; m < 4; ++m) acc[m] += u[m];
        } else {
            float e[4][2];
            float E = 0.f;
#pragma unroll
            for (int m = 0; m < 4; ++m)
#pragma unroll
                for (int jp = 0; jp < 2; ++jp) {
                    const int rb = jp * 8;
                    float pj = u[m][rb + 0] * vv[m][jp][0] +
                               u[m][rb + 1] * vv[m][jp][1] +
                               u[m][rb + 2] * vv[m][jp][2] +
                               u[m][rb + 3] * vv[m][jp][3] +
                               u[m][rb + 4] * vv[m][jp][4] +
                               u[m][rb + 5] * vv[m][jp][5] +
                               u[m][rb + 6] * vv[m][jp][6] +
                               u[m][rb + 7] * vv[m][jp][7];
                    pj += __shfl_xor(pj, 32, 64);  // merge k-halves
                    const float ee = __expf(pj);   // |p| bounded; f32-safe
                    e[m][jp] = ee;
                    E += ee;
                }
            if (h == 0) ebuf[t & 1][jg][l31] = E;
            bar_lds();  // lgkm-only: DMA for t+1 stays in flight
            const float Et = ebuf[t & 1][0][l31] + ebuf[t & 1][1][l31] +
                             ebuf[t & 1][2][l31] + ebuf[t & 1][3][l31];
            const float rr = __builtin_amdgcn_rcpf(Et);
#pragma unroll
            for (int m = 0; m < 4; ++m)
#pragma unroll
                for (int jp = 0; jp < 2; ++jp) {
                    const float c = e[m][jp] * rr;
#pragma unroll
                    for (int q = 0; q < 8; ++q)
                        acc[m][jp * 8 + q] += c * u[m][jp * 8 + q];
                }
        }

        if (t < GI - 1) {
            bar_all();  // t+1 DMA landed; all waves done reading wlds[p]
            if (t < GI - 2) STAGE(t + 2, p);  // overwrite freed buffer
        }
    }
#undef STAGE

    // part[ic][s][b]: per (m,r) two 128-B b-contiguous wave segments
#pragma unroll
    for (int m = 0; m < 4; ++m)
#pragma unroll
        for (int r = 0; r < 16; ++r) {
            const int k = (r & 3) + 8 * ((r >> 2) & 1) + 4 * h;
            const int s = (jg * 8 + m * 2 + (r >> 3)) * 16 + k;
            part[((size_t)ic * JK + s) * 64 + b] = acc[m][r];
        }
}

// ---------------------------------------------------------------------------
// redA: grid 256 = j(32) x pg(8), 512 thr. Sums 32 partials for j's slab
// (1024 floats) via fully-coalesced 4KB rows. part2[pg][j][1024].
// ---------------------------------------------------------------------------
__global__ __launch_bounds__(512)
void caps_redA(const float* __restrict__ part, float* __restrict__ part2) {
    const int j = blockIdx.x >> 3, pg = blockIdx.x & 3 | ((blockIdx.x & 7) & ~3);
    const int pgg = blockIdx.x & 7;
    const int e2 = threadIdx.x * 2;
    float s0 = 0.f, s1 = 0.f;
#pragma unroll 4
    for (int p = pgg * 32; p < pgg * 32 + 32; ++p) {
        const float2 v = *reinterpret_cast<const float2*>(
            part + (size_t)p * (JK * 64) + j * 1024 + e2);
        s0 += v.x; s1 += v.y;
    }
    float2 o; o.x = s0; o.y = s1;
    *reinterpret_cast<float2*>(part2 + ((size_t)pgg * 32 + j) * 1024 + e2) = o;
    (void)pg;
}

// ---------------------------------------------------------------------------
// redB: grid 32 (j), 512 thr. Folds 8 pg + squash (norm over k per b).
// MODE 0: vsum = squash(s/32). MODE 1: vsum += squash(s). MODE 2: out.
// slab element e = k*64 + b; vsum[j*1024 + e]; out[b][j][k].
// ---------------------------------------------------------------------------
template <int MODE>
__global__ __launch_bounds__(512)
void caps_redB(const float* __restrict__ part2, float* __restrict__ vsum,
               float* __restrict__ out) {
    __shared__ float sq[1024];
    __shared__ float sc[64];
    const int j = blockIdx.x;
    const int tid = threadIdx.x;
    const int e2 = tid * 2;
    float s0 = 0.f, s1 = 0.f;
#pragma unroll
    for (int pg = 0; pg < 8; ++pg) {
        const float2 v = *reinterpret_cast<const float2*>(
            part2 + ((size_t)pg * 32 + j) * 1024 + e2);
        s0 += v.x; s1 += v.y;
    }
    if (MODE == 0) { s0 *= (1.f / 32.f); s1 *= (1.f / 32.f); }
    sq[e2] = s0; sq[e2 + 1] = s1;
    __syncthreads();
    if (tid < 64) {
        float nn = 0.f;
#pragma unroll
        for (int k = 0; k < 16; ++k) {
            const float v = sq[k * 64 + tid];
            nn += v * v;
        }
        sc[tid] = nn / ((1.f + nn) * sqrtf(nn + 1e-7f));
    }
    __syncthreads();
    const float v0 = sq[e2] * sc[e2 & 63];
    const float v1 = sq[e2 + 1] * sc[(e2 + 1) & 63];
    if (MODE == 0) {
        vsum[(size_t)j * 1024 + e2] = v0;
        vsum[(size_t)j * 1024 + e2 + 1] = v1;
    } else if (MODE == 1) {
        vsum[(size_t)j * 1024 + e2] += v0;
        vsum[(size_t)j * 1024 + e2 + 1] += v1;
    } else {
        out[(size_t)(e2 & 63) * JK + j * K_ + (e2 >> 6)] = v0;
        out[(size_t)((e2 + 1) & 63) * JK + j * K_ + ((e2 + 1) >> 6)] = v1;
    }
}

// ---------------------------------------------------------------------------
extern "C" void kernel_launch(void* const* d_in, const int* in_sizes, int n_in,
                              void* d_out, int out_size, void* d_ws,
                              size_t ws_size, hipStream_t stream) {
    const float* x = (const float*)d_in[0];  // [B,I,D] f32
    const float* W = (const float*)d_in[1];  // [I,J,D,K] f32
    float* out = (float*)d_out;              // [B,J,K] f32

    char* ws = (char*)d_ws;
    float* part = (float*)ws;                             // 32 MB  @ 0
    unsigned short* Wbf = (unsigned short*)(ws + MB(36)); // 32 MiB @ 36MB
    unsigned int* xbf = (unsigned int*)(ws + MB(70));     // 4 MiB  @ 70MB
    float* part2 = (float*)(ws + MB(75));                 // 1 MB   @ 75MB
    float* vsum = (float*)(ws + MB(77));                  // 128 KB @ 77MB

    caps_prep<<<I_ + 16, 256, 0, stream>>>(x, W, Wbf, xbf);

    // round 0: uniform c = 1/32
    caps_pass<0><<<NIC * 2, 256, 0, stream>>>(Wbf, (const uint4*)xbf, vsum,
                                              part);
    caps_redA<<<256, 512, 0, stream>>>(part, part2);
    caps_redB<0><<<32, 512, 0, stream>>>(part2, vsum, nullptr);
    // round 1
    caps_pass<1><<<NIC * 2, 256, 0, stream>>>(Wbf, (const uint4*)xbf, vsum,
                                              part);
    caps_redA<<<256, 512, 0, stream>>>(part, part2);
    caps_redB<1><<<32, 512, 0, stream>>>(part2, vsum, nullptr);
    // round 2
    caps_pass<1><<<NIC * 2, 256, 0, stream>>>(Wbf, (const uint4*)xbf, vsum,
                                              part);
    caps_redA<<<256, 512, 0, stream>>>(part, part2);
    caps_redB<2><<<32, 512, 0, stream>>>(part2, vsum, out);
}

// Round 12
// 203.988 us; speedup vs baseline: 1.5597x; 1.5597x over previous
//
#include <hip/hip_runtime.h>
#include <hip/hip_bf16.h>

// CapsuleLayer dynamic routing. B=64, I=2048, D=16, J=32, K=16, routings=3.
// Structure: uhat never hits HBM; pass recomputes u_hat (MFMA 16x16x32,
// proven maps, absmax 0.0039) and uses b_t = u_hat . vsum linearity.
// Round 23: r17's pass VERBATIM (best measured structure; r22's DMA rewrite
// spilled: VGPR 256, +105MB scratch writes — reverted). The real recurring
// tax: EVERY reduction since r15 walked partials at 128-KB p-stride
// (r21/r22 measured ~30us each by subtraction; r16's squashN had the same
// layout => r16 passes were ~40us, squash ~24us). Fix = layout, not
// schedule: part[jq][ic][(j&1)*1024 + k*64 + b] (jq=j>>1) makes each
// jq-group's 256 partials ONE contiguous 2MB region.
//  - redA: grid 16jq x 16pb, 512thr float4 — 128KB fully-contiguous stream
//    per block -> part2 (2MB).
//  - redB: grid 16, folds 16 sub-partials (8KB stride), in-LDS squash
//    (norm over k at stride 64), canonical vsum/out writes (pass vv loads
//    unchanged: vsum[b][jk]).
// Lessons: never force min-waves (r8); coalesced stores (r13); hipcc drains
// vmcnt at __syncthreads -> raw lgkm-only barriers in pass (r16); no
// grid.sync (r19); parenthesize byte offsets (r20); no runtime-indexed
// pointer arrays / STAGE macros — they spilled (r22).

#define B_ 64
#define I_ 2048
#define D_ 16
#define J_ 32
#define K_ 16
#define JK 512    // J_*K_
#define NBLK 256  // pass grid; part = 16*256*2048*4 = 32MB
#define GI 8      // i's per block
#define MB(n) ((size_t)(n) << 20)

typedef __attribute__((ext_vector_type(8))) short short8;
typedef __attribute__((ext_vector_type(4))) float float4v;

__device__ __forceinline__ unsigned short f2bf(float f) {
    union { float f; unsigned int i; } v;
    v.f = f;
    const unsigned int x = v.i;
    return (unsigned short)((x + 0x7fffu + ((x >> 16) & 1u)) >> 16);  // RNE
}

// LDS-only barrier: no vmcnt drain (r16 lesson).
__device__ __forceinline__ void bar_lds() {
    asm volatile("s_waitcnt lgkmcnt(0)\n\ts_barrier" ::: "memory");
}

// ---------------------------------------------------------------------------
// Routing pass — r17 body verbatim (proven fastest), only the partial-store
// layout changed. MODE 0: acc += u_hat. MODE 1: acc += softmax * u_hat.
// Grid NBLK x 512. Wave wv: bt = wv&3 (b-tile of 16), jh = wv>>2 (j-half).
// Per lane (l15, quad): b = bt*16+l15; MFMA j gives u_hat[b][j][quad*4+r].
// ---------------------------------------------------------------------------
template <int MODE>
__global__ __launch_bounds__(512)
void caps_pass(const float* __restrict__ x, const float* __restrict__ W,
               const float* __restrict__ vsum, float* __restrict__ part) {
    __shared__ unsigned short wlds[2][32 * 384];  // 48 KB double-buffered W
    __shared__ unsigned short zbuf[8];            // zeros for d=16..31 quads
    __shared__ float ebuf[2][4][2][16];           // per-half exp-sum exchange
    const int tid = threadIdx.x;
    const int lane = tid & 63;
    const int wv = tid >> 6;   // 0..7
    const int bt = wv & 3;     // b-tile index
    const int jh = wv >> 2;    // j-half index
    const int quad = lane >> 4;
    const int l15 = lane & 15;
    const int b = bt * 16 + l15;
    const int i0 = blockIdx.x * GI;

    if (tid < 8) zbuf[tid] = 0;

    // vsum fragment: vv[jj] = vsum[b][jh*16+jj][quad*4 .. +3] (MODE 1 only)
    float4 vv[16];
    if (MODE == 1) {
#pragma unroll
        for (int jj = 0; jj < 16; ++jj)
            vv[jj] = reinterpret_cast<const float4*>(
                vsum + b * JK + (jh * 16 + jj) * 16 + quad * 4)[0];
    }

    float4 acc2[16];
#pragma unroll
    for (int jj = 0; jj < 16; ++jj) {
        acc2[jj].x = 0.f; acc2[jj].y = 0.f;
        acc2[jj].z = 0.f; acc2[jj].w = 0.f;
    }

    const int sk = tid & 15;   // stage: k lane
    const int sj = tid >> 4;   // stage: j row 0..31 (512 threads cover all)
    const float* wp = W + (size_t)i0 * (J_ * D_ * K_) + sj * (D_ * K_) + sk;
    const float* xp = x + ((size_t)b * I_ + i0) * D_ + (quad & 1) * 8;

    // ---- prologue: load i0's W and x into registers, stage buf 0 ----
    float vals[16];
#pragma unroll
    for (int d = 0; d < 16; ++d) vals[d] = wp[d * K_];
    float4 xr0 = reinterpret_cast<const float4*>(xp)[0];
    float4 xr1 = reinterpret_cast<const float4*>(xp)[1];
    {
        unsigned int pk[8];
#pragma unroll
        for (int q = 0; q < 8; ++q)
            pk[q] = ((unsigned int)f2bf(vals[2 * q + 1]) << 16) |
                    f2bf(vals[2 * q]);
        uint4* dst = reinterpret_cast<uint4*>(&wlds[0][sj * 384 + sk * 24]);
        uint4 w0; w0.x = pk[0]; w0.y = pk[1]; w0.z = pk[2]; w0.w = pk[3];
        uint4 w1; w1.x = pk[4]; w1.y = pk[5]; w1.z = pk[6]; w1.w = pk[7];
        dst[0] = w0; dst[1] = w1;
    }

    for (int t = 0; t < GI; ++t) {
        const int p = t & 1;

        bar_lds();  // B1: wlds[p] (staged end of prev iter) visible

        // ---- prefetch i_{t+1}: issue after the barrier (nothing drains
        //      vmcnt); consume after both sweeps ----
        float nv[16];
        float4 nx0, nx1;
        if (t < GI - 1) {
            const float* wn = wp + (size_t)(t + 1) * (J_ * D_ * K_);
#pragma unroll
            for (int d = 0; d < 16; ++d) nv[d] = wn[d * K_];
            const float* xn = xp + (t + 1) * D_;
            nx0 = reinterpret_cast<const float4*>(xn)[0];
            nx1 = reinterpret_cast<const float4*>(xn)[1];
        }

        // pack current x frag (registers already loaded)
        union { uint4 u; short8 s; } bfrag;
        bfrag.u.x = ((unsigned int)f2bf(xr0.y) << 16) | f2bf(xr0.x);
        bfrag.u.y = ((unsigned int)f2bf(xr0.w) << 16) | f2bf(xr0.z);
        bfrag.u.z = ((unsigned int)f2bf(xr1.y) << 16) | f2bf(xr1.x);
        bfrag.u.w = ((unsigned int)f2bf(xr1.w) << 16) | f2bf(xr1.z);
        if (quad >= 2) { bfrag.u.x = 0; bfrag.u.y = 0; bfrag.u.z = 0; bfrag.u.w = 0; }

        const unsigned short* aptr =
            (quad >= 2) ? zbuf : (&wlds[p][0] + l15 * 24 + (quad & 1) * 8);
        const int astride = (quad >= 2) ? 0 : 384;

        if (MODE == 0) {
#pragma unroll
            for (int jj = 0; jj < 16; ++jj) {
                const int j = jh * 16 + jj;
                union { uint4 u; short8 s; } af;
                af.u = *reinterpret_cast<const uint4*>(aptr + (size_t)j * astride);
                float4v a = {0.f, 0.f, 0.f, 0.f};
                a = __builtin_amdgcn_mfma_f32_16x16x32_bf16(af.s, bfrag.s, a,
                                                            0, 0, 0);
                acc2[jj].x += a[0]; acc2[jj].y += a[1];
                acc2[jj].z += a[2]; acc2[jj].w += a[3];
            }
        } else {
            // sweep 1: p[b,j] = sum_k u_hat*vsum, exp, half-denominator
            float e[16];
            float E = 0.f;
#pragma unroll
            for (int jj = 0; jj < 16; ++jj) {
                const int j = jh * 16 + jj;
                union { uint4 u; short8 s; } af;
                af.u = *reinterpret_cast<const uint4*>(aptr + (size_t)j * astride);
                float4v a = {0.f, 0.f, 0.f, 0.f};
                a = __builtin_amdgcn_mfma_f32_16x16x32_bf16(af.s, bfrag.s, a,
                                                            0, 0, 0);
                float pj = a[0] * vv[jj].x + a[1] * vv[jj].y +
                           a[2] * vv[jj].z + a[3] * vv[jj].w;
                pj += __shfl_xor(pj, 16, 64);  // cross-quad k-reduce
                pj += __shfl_xor(pj, 32, 64);
                const float ee = __expf(pj);  // |p| bounded; f32-safe
                e[jj] = ee;
                E += ee;
            }
            if (quad == 0) ebuf[p][bt][jh][l15] = E;
            bar_lds();  // B2: ebuf[p] visible; prefetch globals in flight
            const float S = E + ebuf[p][bt][1 - jh][l15];
            const float r = __builtin_amdgcn_rcpf(S);
            // sweep 2: re-MFMA u_hat, accumulate c * u_hat
#pragma unroll
            for (int jj = 0; jj < 16; ++jj) {
                const int j = jh * 16 + jj;
                union { uint4 u; short8 s; } af;
                af.u = *reinterpret_cast<const uint4*>(aptr + (size_t)j * astride);
                float4v a = {0.f, 0.f, 0.f, 0.f};
                a = __builtin_amdgcn_mfma_f32_16x16x32_bf16(af.s, bfrag.s, a,
                                                            0, 0, 0);
                const float c = e[jj] * r;
                acc2[jj].x += c * a[0]; acc2[jj].y += c * a[1];
                acc2[jj].z += c * a[2]; acc2[jj].w += c * a[3];
            }
        }

        // ---- consume prefetch: pack + stage into wlds[p^1] ----
        if (t < GI - 1) {
            unsigned int pk[8];
#pragma unroll
            for (int q = 0; q < 8; ++q)
                pk[q] = ((unsigned int)f2bf(nv[2 * q + 1]) << 16) |
                        f2bf(nv[2 * q]);
            uint4* dst =
                reinterpret_cast<uint4*>(&wlds[p ^ 1][sj * 384 + sk * 24]);
            uint4 w0; w0.x = pk[0]; w0.y = pk[1]; w0.z = pk[2]; w0.w = pk[3];
            uint4 w1; w1.x = pk[4]; w1.y = pk[5]; w1.z = pk[6]; w1.w = pk[7];
            dst[0] = w0; dst[1] = w1;
            xr0 = nx0; xr1 = nx1;
        }
    }

    // ---- store partial, contiguous-group layout ----
    // part[jq][ic][(j&1)*1024 + k*64 + b], jq = j>>1 = jh*8 + (jj>>1).
    // Per store instr: 16 lanes (l15) x 4B = 64B segments, 4 quads 256B
    // apart — 64B-granule coalesced, all within the block's jq regions.
#pragma unroll
    for (int jj = 0; jj < 16; ++jj) {
        const int jq = jh * 8 + (jj >> 1);
        float* gp = part + ((size_t)jq * NBLK + blockIdx.x) * 2048 +
                    (jj & 1) * 1024 + b;
        gp[(quad * 4 + 0) * 64] = acc2[jj].x;
        gp[(quad * 4 + 1) * 64] = acc2[jj].y;
        gp[(quad * 4 + 2) * 64] = acc2[jj].z;
        gp[(quad * 4 + 3) * 64] = acc2[jj].w;
    }
}

// ---------------------------------------------------------------------------
// redA: grid 256 = jq(16) x pb(16), 512 thr. Sums 16 ic-slabs: reads
// 128 KB FULLY CONTIGUOUS per block (float4/thread). part2[jq][pb][2048].
// ---------------------------------------------------------------------------
__global__ __launch_bounds__(512)
void caps_redA(const float* __restrict__ part, float* __restrict__ part2) {
    const int jq = blockIdx.x >> 4, pb = blockIdx.x & 15;
    const int e4 = threadIdx.x * 4;
    float4 s = {0.f, 0.f, 0.f, 0.f};
#pragma unroll 4
    for (int icb = 0; icb < 16; ++icb) {
        const float4 v = *reinterpret_cast<const float4*>(
            part + ((size_t)jq * NBLK + pb * 16 + icb) * 2048 + e4);
        s.x += v.x; s.y += v.y; s.z += v.z; s.w += v.w;
    }
    *reinterpret_cast<float4*>(part2 + ((size_t)jq * 16 + pb) * 2048 + e4) = s;
}

// ---------------------------------------------------------------------------
// redB: grid 16 (jq), 512 thr. Folds 16 sub-partials + in-LDS squash.
// Group element e = (j&1)*1024 + k*64 + b. Norm over k (stride 64).
// MODE 0: vsum = squash(s/32). MODE 1: vsum += squash(s). MODE 2: out.
// ---------------------------------------------------------------------------
template <int MODE>
__global__ __launch_bounds__(512)
void caps_redB(const float* __restrict__ part2, float* __restrict__ vsum,
               float* __restrict__ out) {
    __shared__ float sq[2048];
    __shared__ float sc[128];
    const int jq = blockIdx.x;
    const int tid = threadIdx.x;
    const int e4 = tid * 4;
    float4 s = {0.f, 0.f, 0.f, 0.f};
#pragma unroll
    for (int pb = 0; pb < 16; ++pb) {
        const float4 v = *reinterpret_cast<const float4*>(
            part2 + ((size_t)jq * 16 + pb) * 2048 + e4);
        s.x += v.x; s.y += v.y; s.z += v.z; s.w += v.w;
    }
    if (MODE == 0) {
        s.x *= (1.f / 32.f); s.y *= (1.f / 32.f);
        s.z *= (1.f / 32.f); s.w *= (1.f / 32.f);
    }
    *reinterpret_cast<float4*>(&sq[e4]) = s;
    __syncthreads();
    if (tid < 128) {  // j1 = tid>>6, b = tid&63
        const int j1 = tid >> 6, bb = tid & 63;
        float nn = 0.f;
#pragma unroll
        for (int k = 0; k < 16; ++k) {
            const float v = sq[j1 * 1024 + k * 64 + bb];
            nn += v * v;
        }
        sc[tid] = nn / ((1.f + nn) * sqrtf(nn + 1e-7f));
    }
    __syncthreads();
#pragma unroll
    for (int q = 0; q < 4; ++q) {
        const int e = e4 + q;
        const int j1 = e >> 10, k = (e >> 6) & 15, bb = e & 63;
        const float v = sq[e] * sc[j1 * 64 + bb];
        const int j = jq * 2 + j1;
        if (MODE == 0)      vsum[(size_t)bb * JK + j * 16 + k] = v;
        else if (MODE == 1) vsum[(size_t)bb * JK + j * 16 + k] += v;
        else                out[(size_t)bb * JK + j * 16 + k] = v;
    }
}

// ---------------------------------------------------------------------------
extern "C" void kernel_launch(void* const* d_in, const int* in_sizes, int n_in,
                              void* d_out, int out_size, void* d_ws,
                              size_t ws_size, hipStream_t stream) {
    const float* x = (const float*)d_in[0];  // [B,I,D] f32
    const float* W = (const float*)d_in[1];  // [I,J,D,K] f32
    float* out = (float*)d_out;              // [B,J,K] f32

    char* ws = (char*)d_ws;
    float* part = (float*)ws;                 // [16][256][2048] f32 = 32 MB
    float* part2 = (float*)(ws + MB(36));     // [16][16][2048] f32 = 2 MB
    float* vsum = (float*)(ws + MB(40));      // [B][JK] f32 = 128 KB

    // round 0: uniform c = 1/32
    caps_pass<0><<<NBLK, 512, 0, stream>>>(x, W, nullptr, part);
    caps_redA<<<256, 512, 0, stream>>>(part, part2);
    caps_redB<0><<<16, 512, 0, stream>>>(part2, vsum, nullptr);
    // round 1
    caps_pass<1><<<NBLK, 512, 0, stream>>>(x, W, vsum, part);
    caps_redA<<<256, 512, 0, stream>>>(part, part2);
    caps_redB<1><<<16, 512, 0, stream>>>(part2, vsum, nullptr);
    // round 2
    caps_pass<1><<<NBLK, 512, 0, stream>>>(x, W, vsum, part);
    caps_redA<<<256, 512, 0, stream>>>(part, part2);
    caps_redB<2><<<16, 512, 0, stream>>>(part2, vsum, out);
}